// Round 3
// baseline (15.756 us; speedup 1.0000x reference)
//
#include <hip/hip_runtime.h>

// State: 8192 rows x 64 cols complex. Row r: m = r & 63 (kernel A's bits 0..5),
// h = r >> 6 (kernel B's bits 6..12). Gate on angle[i] acts on row-bit (12-i).
// float4 element = (re,im) x 2 adjacent cols.
// ws layout = exactly B's LDS slot order so B's global_load_lds is contiguous:
//   ws4[(q*64 + m)*512 + h*4 + (cpB ^ swzB(h))], q = 8-col oct (0..7), cpB = col-pair in oct.
#define PLANE (8192 * 64)

__device__ __forceinline__ void gate_coeffs(float theta, float& a, float& s) {
    // truncated series, CUTOFF=10: a ~ cos(theta/2) thru t^10, s ~ sin(theta/2) thru t^9
    float t = 0.5f * theta;
    float u = t * t;
    s = t * (1.f + u * (-1.f/6.f + u * (1.f/120.f + u * (-1.f/5040.f + u * (1.f/362880.f)))));
    a = 1.f + u * (-0.5f + u * (1.f/24.f + u * (-1.f/720.f + u * (1.f/40320.f + u * (-1.f/3628800.f)))));
}

// v = (reA, imA, reB, imB) for two columns of one row; RX pair update.
__device__ __forceinline__ void bf(float4& v0, float4& v1, float a, float s) {
    float4 n0, n1;
    n0.x = a * v0.x + s * v1.y;  n0.y = a * v0.y - s * v1.x;
    n0.z = a * v0.z + s * v1.w;  n0.w = a * v0.w - s * v1.z;
    n1.x = a * v1.x + s * v0.y;  n1.y = a * v1.y - s * v0.x;
    n1.z = a * v1.z + s * v0.w;  n1.w = a * v1.w - s * v0.z;
    v0 = n0; v1 = n1;
}

// LDS bank swizzles (keep strided radix reads at b128 baseline)
__device__ __forceinline__ int swzA(int row, int cp) {            // A: [64 rows][8 cps]
    return row * 8 + (cp ^ ((row ^ (row >> 3)) & 7));
}
__device__ __forceinline__ int sB(int h) { return (h ^ (h >> 2) ^ (h >> 4)) & 3; }
__device__ __forceinline__ int swzB(int h, int cp) {              // B: [128 h][4 cps]
    return h * 4 + (cp ^ sB(h));
}

// Kernel A: row-bits 0..5 (angle[12]..angle[7]).
// Block = 64 rows (h = g fixed) x 16 cols. grid = 128 * 4 = 512, 128 threads.
__global__ __launch_bounds__(128) void rx_low(const float* __restrict__ xr,
                                              const float* __restrict__ xi,
                                              const float* __restrict__ angle,
                                              float4* __restrict__ ws4) {
    __shared__ float4 la[512];         // 8 KB
    const int t  = threadIdx.x;
    const int g  = blockIdx.x >> 2;    // 0..127 (= h)
    const int qq = blockIdx.x & 3;     // 16-col quarter

    float a0,s0,a1,s1,a2,s2,a3,s3,a4,s4,a5,s5;
    gate_coeffs(angle[12], a0, s0);    // bit 0
    gate_coeffs(angle[11], a1, s1);    // bit 1
    gate_coeffs(angle[10], a2, s2);    // bit 2
    gate_coeffs(angle[9],  a3, s3);    // bit 3
    gate_coeffs(angle[8],  a4, s4);    // bit 4
    gate_coeffs(angle[7],  a5, s5);    // bit 5

    const float4* xr4 = (const float4*)xr;
    const float4* xi4 = (const float4*)xi;

    #pragma unroll
    for (int k = 0; k < 2; ++k) {      // 256 (row,f4) slots / 128 threads
        int j   = t + 128 * k;
        int row = j >> 2, f4 = j & 3;
        int ga  = (g * 64 + row) * 16 + qq * 4 + f4;
        float4 re = xr4[ga], im = xi4[ga];
        la[swzA(row, 2 * f4)]     = make_float4(re.x, im.x, re.y, im.y);
        la[swzA(row, 2 * f4 + 1)] = make_float4(re.z, im.z, re.w, im.w);
    }
    __syncthreads();

    const int cp = t & 7, grp = t >> 3;   // grp 0..15

    {   // RT1: bits 0,1
        int r0 = grp * 4;
        float4 v0 = la[swzA(r0 + 0, cp)], v1 = la[swzA(r0 + 1, cp)];
        float4 v2 = la[swzA(r0 + 2, cp)], v3 = la[swzA(r0 + 3, cp)];
        bf(v0, v1, a0, s0); bf(v2, v3, a0, s0);
        bf(v0, v2, a1, s1); bf(v1, v3, a1, s1);
        la[swzA(r0 + 0, cp)] = v0; la[swzA(r0 + 1, cp)] = v1;
        la[swzA(r0 + 2, cp)] = v2; la[swzA(r0 + 3, cp)] = v3;
    }
    __syncthreads();
    {   // RT2: bits 2,3
        int base = ((grp >> 2) << 4) | (grp & 3);
        int r0 = base, r1 = base + 4, r2 = base + 8, r3 = base + 12;
        float4 v0 = la[swzA(r0, cp)], v1 = la[swzA(r1, cp)];
        float4 v2 = la[swzA(r2, cp)], v3 = la[swzA(r3, cp)];
        bf(v0, v1, a2, s2); bf(v2, v3, a2, s2);
        bf(v0, v2, a3, s3); bf(v1, v3, a3, s3);
        la[swzA(r0, cp)] = v0; la[swzA(r1, cp)] = v1;
        la[swzA(r2, cp)] = v2; la[swzA(r3, cp)] = v3;
    }
    __syncthreads();
    {   // RT3: bits 4,5
        int r0 = grp, r1 = grp + 16, r2 = grp + 32, r3 = grp + 48;
        float4 v0 = la[swzA(r0, cp)], v1 = la[swzA(r1, cp)];
        float4 v2 = la[swzA(r2, cp)], v3 = la[swzA(r3, cp)];
        bf(v0, v1, a4, s4); bf(v2, v3, a4, s4);
        bf(v0, v2, a5, s5); bf(v1, v3, a5, s5);
        la[swzA(r0, cp)] = v0; la[swzA(r1, cp)] = v1;
        la[swzA(r2, cp)] = v2; la[swzA(r3, cp)] = v3;
    }
    __syncthreads();

    const int sbg = sB(g);             // B's swizzle for h = g: constant per block
    #pragma unroll
    for (int k = 0; k < 4; ++k) {      // 512 float4 / 128 threads
        int j  = t + 128 * k;
        int m  = j >> 3, cp8 = j & 7;
        int q  = qq * 2 + (cp8 >> 2), cb = cp8 & 3;
        ws4[(q * 64 + m) * 512 + g * 4 + (cb ^ sbg)] = la[swzA(m, cp8)];
    }
}

// Kernel B: row-bits 6..12 (angle[6]..angle[0]).
// Block = 128 h (m fixed) x 8 cols. grid = 64 * 8 = 512, 128 threads.
__global__ __launch_bounds__(128) void rx_high(const float* __restrict__ angle,
                                               const float4* __restrict__ ws4,
                                               float* __restrict__ out) {
    __shared__ float4 lb[512];         // 8 KB
    const int t = threadIdx.x;
    const int m = blockIdx.x >> 3;     // 0..63
    const int q = blockIdx.x & 7;      // 8-col oct

    float a0,s0,a1,s1,a2,s2,a3,s3,a4,s4,a5,s5,a6,s6;
    gate_coeffs(angle[6], a0, s0);     // h-bit 0
    gate_coeffs(angle[5], a1, s1);     // h-bit 1
    gate_coeffs(angle[4], a2, s2);     // h-bit 2
    gate_coeffs(angle[3], a3, s3);     // h-bit 3
    gate_coeffs(angle[2], a4, s4);     // h-bit 4
    gate_coeffs(angle[1], a5, s5);     // h-bit 5
    gate_coeffs(angle[0], a6, s6);     // h-bit 6

    const float4* src = ws4 + (size_t)(q * 64 + m) * 512;   // contiguous 8 KB
    typedef const __attribute__((address_space(1))) unsigned int* g32;
    typedef __attribute__((address_space(3))) unsigned int* l32;
    #pragma unroll
    for (int k = 0; k < 4; ++k) {
        int slot = t + 128 * k;
        __builtin_amdgcn_global_load_lds((g32)(src + slot), (l32)(lb + slot), 16, 0, 0);
    }
    asm volatile("s_waitcnt vmcnt(0)" ::: "memory");
    __syncthreads();

    const int cp = t & 3, grp = t >> 2;   // grp 0..31

    {   // RT1: h-bits 0,1
        int h0 = grp * 4;
        float4 v0 = lb[swzB(h0 + 0, cp)], v1 = lb[swzB(h0 + 1, cp)];
        float4 v2 = lb[swzB(h0 + 2, cp)], v3 = lb[swzB(h0 + 3, cp)];
        bf(v0, v1, a0, s0); bf(v2, v3, a0, s0);
        bf(v0, v2, a1, s1); bf(v1, v3, a1, s1);
        lb[swzB(h0 + 0, cp)] = v0; lb[swzB(h0 + 1, cp)] = v1;
        lb[swzB(h0 + 2, cp)] = v2; lb[swzB(h0 + 3, cp)] = v3;
    }
    __syncthreads();
    {   // RT2: h-bits 2,3
        int base = ((grp >> 2) << 4) | (grp & 3);
        int h0 = base, h1 = base + 4, h2 = base + 8, h3 = base + 12;
        float4 v0 = lb[swzB(h0, cp)], v1 = lb[swzB(h1, cp)];
        float4 v2 = lb[swzB(h2, cp)], v3 = lb[swzB(h3, cp)];
        bf(v0, v1, a2, s2); bf(v2, v3, a2, s2);
        bf(v0, v2, a3, s3); bf(v1, v3, a3, s3);
        lb[swzB(h0, cp)] = v0; lb[swzB(h1, cp)] = v1;
        lb[swzB(h2, cp)] = v2; lb[swzB(h3, cp)] = v3;
    }
    __syncthreads();
    {   // RT3: h-bits 4,5
        int base = ((grp >> 4) << 6) | (grp & 15);
        int h0 = base, h1 = base + 16, h2 = base + 32, h3 = base + 48;
        float4 v0 = lb[swzB(h0, cp)], v1 = lb[swzB(h1, cp)];
        float4 v2 = lb[swzB(h2, cp)], v3 = lb[swzB(h3, cp)];
        bf(v0, v1, a4, s4); bf(v2, v3, a4, s4);
        bf(v0, v2, a5, s5); bf(v1, v3, a5, s5);
        lb[swzB(h0, cp)] = v0; lb[swzB(h1, cp)] = v1;
        lb[swzB(h2, cp)] = v2; lb[swzB(h3, cp)] = v3;
    }
    __syncthreads();
    {   // RT4: h-bit 6 (radix-2, 2 pairs/thread)
        #pragma unroll
        for (int pp = 0; pp < 2; ++pp) {
            int p  = t + 128 * pp;
            int cpP = p & 3, hl = p >> 2;    // hl 0..63
            float4 v0 = lb[swzB(hl, cpP)], v1 = lb[swzB(hl + 64, cpP)];
            bf(v0, v1, a6, s6);
            lb[swzB(hl, cpP)] = v0; lb[swzB(hl + 64, cpP)] = v1;
        }
    }
    __syncthreads();

    float4* or4 = (float4*)out;
    float4* oi4 = (float4*)(out + PLANE);
    #pragma unroll
    for (int k = 0; k < 4; ++k) {      // 512 stores: (h, plane, f4c)
        int j   = t + 128 * k;
        int h   = j >> 2, pl = (j >> 1) & 1, f4c = j & 1;
        float4 v0 = lb[swzB(h, f4c * 2)];
        float4 v1 = lb[swzB(h, f4c * 2 + 1)];
        float4 val = pl ? make_float4(v0.y, v0.w, v1.y, v1.w)
                        : make_float4(v0.x, v0.z, v1.x, v1.z);
        float4* dst = pl ? oi4 : or4;
        dst[((h << 6) | m) * 16 + q * 2 + f4c] = val;
    }
}

extern "C" void kernel_launch(void* const* d_in, const int* in_sizes, int n_in,
                              void* d_out, int out_size, void* d_ws, size_t ws_size,
                              hipStream_t stream) {
    const float* xr    = (const float*)d_in[0];
    const float* xi    = (const float*)d_in[1];
    const float* angle = (const float*)d_in[2];
    float*  out = (float*)d_out;
    float4* ws4 = (float4*)d_ws;

    rx_low<<<512, 128, 0, stream>>>(xr, xi, angle, ws4);
    rx_high<<<512, 128, 0, stream>>>(angle, ws4, out);
}